// Round 1
// baseline (1222.423 us; speedup 1.0000x reference)
//
#include <hip/hip_runtime.h>

#define DEVINL __device__ __forceinline__

typedef __bf16 bf16x8 __attribute__((ext_vector_type(8)));
typedef float  f32x4  __attribute__((ext_vector_type(4)));

DEVINL unsigned short f2bf(float f) {
  union { float f; unsigned int u; } v; v.f = f;
  unsigned int u = v.u;
  return (unsigned short)((u + 0x7fffu + ((u >> 16) & 1u)) >> 16);
}
DEVINL float bf2f(unsigned short b) {
  union { unsigned int u; float f; } v; v.u = ((unsigned int)b) << 16;
  return v.f;
}
DEVINL __bf16 fbf(float f) {
  unsigned short u = f2bf(f);
  return __builtin_bit_cast(__bf16, u);
}

#define GLD_LDS16(SRC, DST) \
  __builtin_amdgcn_global_load_lds((const __attribute__((address_space(1))) void*)(SRC), \
                                   (__attribute__((address_space(3))) void*)(DST), 16, 0, 0)

// ---------------------------------------------------------------------------
// GEMM: C[M,N] = A[M,K] * B[N,K]^T  (both operands K-contiguous row-major)
// 128x128 tile, 4 waves (2x2), each wave 64x64 via 4x4 frags of 16x16x32 bf16.
// EPI: 0=f32 store (ACC: +=), 1=bf16 store, 2=bf16 transposed store,
//      3=f32 store + res, 4=bf16 relu(x+bias), 5=f32 x+bias+res
// AF32: A operand is f32 in memory (converted to bf16 after LDS staging).
// Batched over blockIdx.z with z -> (bb = z/H, hh = z%H) offsets.
// ---------------------------------------------------------------------------
template<int EPI, bool ACC, bool AF32>
__global__ __launch_bounds__(256) void gemm_bt(
    const void* __restrict__ Ap, const unsigned short* __restrict__ Bp, void* __restrict__ Cp,
    const float* __restrict__ bias, const float* __restrict__ res,
    int M, int N, int K, int lda, int ldb, int ldc, int H,
    long sAb, long sAh, long sBb, long sBh, long sCb, long sCh)
{
  constexpr int ABYTES = AF32 ? 16384 : 8192;
  __shared__ __align__(16) char smem[ABYTES + 8192];
  unsigned short* sB = (unsigned short*)(smem + ABYTES);

  const int tid = threadIdx.x;
  const int w = tid >> 6, l = tid & 63;
  const int wr = w >> 1, wc = w & 1;
  const int ntn = N >> 7;
  const int tm = (int)blockIdx.x / ntn;
  const int tn = (int)blockIdx.x - tm * ntn;
  const int z = blockIdx.z;
  const int bb = z / H, hh = z - bb * H;
  const long offA = (long)bb * sAb + (long)hh * sAh;
  const long offB = (long)bb * sBb + (long)hh * sBh;
  const long offC = (long)bb * sCb + (long)hh * sCh;

  f32x4 zero = {0.f, 0.f, 0.f, 0.f};
  f32x4 acc[4][4];
  #pragma unroll
  for (int m = 0; m < 4; ++m)
    #pragma unroll
    for (int n = 0; n < 4; ++n) acc[m][n] = zero;

  for (int k0 = 0; k0 < K; k0 += 32) {
    __syncthreads();
    // ---- stage A tile (128 rows x 32 k) ----
    if constexpr (!AF32) {
      const unsigned short* A = (const unsigned short*)Ap;
      const int rl = l >> 2, cl = (l & 3) << 3;
      #pragma unroll
      for (int i = 0; i < 2; ++i) {
        const unsigned short* src = A + offA + (long)(tm*128 + w*32 + i*16 + rl) * lda + (k0 + cl);
        unsigned short* dst = (unsigned short*)smem + (w*32 + i*16) * 32;
        GLD_LDS16(src, dst);
      }
    } else {
      const float* A = (const float*)Ap;
      const int rl = l >> 3, cl = (l & 7) << 2;
      #pragma unroll
      for (int i = 0; i < 4; ++i) {
        const float* src = A + offA + (long)(tm*128 + w*32 + i*8 + rl) * lda + (k0 + cl);
        float* dst = (float*)smem + (w*32 + i*8) * 32;
        GLD_LDS16(src, dst);
      }
    }
    // ---- stage B tile (128 rows x 32 k) ----
    {
      const int rl = l >> 2, cl = (l & 3) << 3;
      #pragma unroll
      for (int i = 0; i < 2; ++i) {
        const unsigned short* src = Bp + offB + (long)(tn*128 + w*32 + i*16 + rl) * ldb + (k0 + cl);
        unsigned short* dst = sB + (w*32 + i*16) * 32;
        GLD_LDS16(src, dst);
      }
    }
    __syncthreads();

    // ---- fragments ----
    bf16x8 af[4], bfr[4];
    if constexpr (!AF32) {
      const unsigned short* sA = (const unsigned short*)smem;
      #pragma unroll
      for (int m = 0; m < 4; ++m) {
        int row = wr*64 + m*16 + (l & 15);
        af[m] = *(const bf16x8*)(sA + row*32 + ((l >> 4) << 3));
      }
    } else {
      const float* sA = (const float*)smem;
      #pragma unroll
      for (int m = 0; m < 4; ++m) {
        int row = wr*64 + m*16 + (l & 15);
        const float* p = sA + row*32 + ((l >> 4) << 3);
        f32x4 v0 = *(const f32x4*)p;
        f32x4 v1 = *(const f32x4*)(p + 4);
        bf16x8 t;
        t[0]=fbf(v0[0]); t[1]=fbf(v0[1]); t[2]=fbf(v0[2]); t[3]=fbf(v0[3]);
        t[4]=fbf(v1[0]); t[5]=fbf(v1[1]); t[6]=fbf(v1[2]); t[7]=fbf(v1[3]);
        af[m] = t;
      }
    }
    #pragma unroll
    for (int n = 0; n < 4; ++n) {
      int row = wc*64 + n*16 + (l & 15);
      bfr[n] = *(const bf16x8*)(sB + row*32 + ((l >> 4) << 3));
    }
    #pragma unroll
    for (int m = 0; m < 4; ++m)
      #pragma unroll
      for (int n = 0; n < 4; ++n)
        acc[m][n] = __builtin_amdgcn_mfma_f32_16x16x32_bf16(af[m], bfr[n], acc[m][n], 0, 0, 0);
  }

  // ---- epilogue ----
  #pragma unroll
  for (int m = 0; m < 4; ++m) {
    #pragma unroll
    for (int n = 0; n < 4; ++n) {
      #pragma unroll
      for (int r = 0; r < 4; ++r) {
        int row = tm*128 + wr*64 + m*16 + ((l >> 4) << 2) + r;
        int col = tn*128 + wc*64 + n*16 + (l & 15);
        float v = acc[m][n][r];
        long ci = offC + (long)row * ldc + col;
        if constexpr (EPI == 0) {
          float* C = (float*)Cp;
          C[ci] = ACC ? (C[ci] + v) : v;
        } else if constexpr (EPI == 1) {
          ((unsigned short*)Cp)[ci] = f2bf(v);
        } else if constexpr (EPI == 2) {
          ((unsigned short*)Cp)[offC + (long)col * ldc + row] = f2bf(v);
        } else if constexpr (EPI == 3) {
          ((float*)Cp)[ci] = v + res[ci];
        } else if constexpr (EPI == 4) {
          ((unsigned short*)Cp)[ci] = f2bf(fmaxf(v + bias[col], 0.f));
        } else if constexpr (EPI == 5) {
          ((float*)Cp)[ci] = v + bias[col] + res[ci];
        }
      }
    }
  }
}

// ---------------------------------------------------------------------------
// LayerNorm over (d_model, seq) per batch: two-stage deterministic reduction.
// ---------------------------------------------------------------------------
__global__ __launch_bounds__(256) void ln_stats1(const float* __restrict__ x, float2* __restrict__ part) {
  __shared__ float2 sred[4];
  int b = blockIdx.y, blk = blockIdx.x;
  const float4* xp = (const float4*)(x + (long)b * 1048576 + (long)blk * 8192);
  float s = 0.f, ss = 0.f;
  for (int i = threadIdx.x; i < 2048; i += 256) {
    float4 v = xp[i];
    s  += v.x + v.y + v.z + v.w;
    ss += v.x*v.x + v.y*v.y + v.z*v.z + v.w*v.w;
  }
  #pragma unroll
  for (int o = 32; o; o >>= 1) { s += __shfl_down(s, o, 64); ss += __shfl_down(ss, o, 64); }
  if ((threadIdx.x & 63) == 0) sred[threadIdx.x >> 6] = make_float2(s, ss);
  __syncthreads();
  if (threadIdx.x == 0) {
    float S = 0.f, SS = 0.f;
    #pragma unroll
    for (int j = 0; j < 4; ++j) { S += sred[j].x; SS += sred[j].y; }
    part[b * 128 + blk] = make_float2(S, SS);
  }
}

__global__ __launch_bounds__(128) void ln_stats2(const float2* __restrict__ part, float2* __restrict__ stats,
                                                 float invN, float eps) {
  __shared__ float2 tmp[2];
  int b = blockIdx.x;
  float2 p = part[b * 128 + threadIdx.x];
  float s = p.x, ss = p.y;
  #pragma unroll
  for (int o = 32; o; o >>= 1) { s += __shfl_down(s, o, 64); ss += __shfl_down(ss, o, 64); }
  if ((threadIdx.x & 63) == 0) tmp[threadIdx.x >> 6] = make_float2(s, ss);
  __syncthreads();
  if (threadIdx.x == 0) {
    float S = tmp[0].x + tmp[1].x, SS = tmp[0].y + tmp[1].y;
    float mu = S * invN;
    float var = SS * invN - mu * mu;
    stats[b] = make_float2(mu, rsqrtf(var + eps));
  }
}

template<bool LO>
__global__ __launch_bounds__(256) void ln_apply(const float* __restrict__ x, const float* __restrict__ g,
                                                const float* __restrict__ be, const float2* __restrict__ stats,
                                                unsigned short* __restrict__ hi, unsigned short* __restrict__ lo) {
  long i = (long)blockIdx.x * 256 + threadIdx.x;   // float4 index, 2M total
  long e = i << 2;
  int b   = (int)(e >> 20);
  int rem = (int)(e & 1048575);
  float2 st = stats[b];
  float4 xv = ((const float4*)x)[i];
  float4 gv = *(const float4*)(g + rem);
  float4 bv = *(const float4*)(be + rem);
  float h0 = (xv.x - st.x) * st.y * gv.x + bv.x;
  float h1 = (xv.y - st.x) * st.y * gv.y + bv.y;
  float h2 = (xv.z - st.x) * st.y * gv.z + bv.z;
  float h3 = (xv.w - st.x) * st.y * gv.w + bv.w;
  ushort4 h;
  h.x = f2bf(h0); h.y = f2bf(h1); h.z = f2bf(h2); h.w = f2bf(h3);
  ((ushort4*)hi)[i] = h;
  if (LO) {
    ushort4 l4;
    l4.x = f2bf(h0 - bf2f(h.x)); l4.y = f2bf(h1 - bf2f(h.y));
    l4.z = f2bf(h2 - bf2f(h.z)); l4.w = f2bf(h3 - bf2f(h.w));
    ((ushort4*)lo)[i] = l4;
  }
}

// ---------------------------------------------------------------------------
// elementwise split/cast to bf16
// ---------------------------------------------------------------------------
__global__ __launch_bounds__(256) void split_bf16(const float* __restrict__ src,
                                                  unsigned short* __restrict__ hi,
                                                  unsigned short* __restrict__ lo) {
  long i = (long)blockIdx.x * 256 + threadIdx.x;
  float4 v = ((const float4*)src)[i];
  ushort4 h, l4;
  h.x = f2bf(v.x); l4.x = f2bf(v.x - bf2f(h.x));
  h.y = f2bf(v.y); l4.y = f2bf(v.y - bf2f(h.y));
  h.z = f2bf(v.z); l4.z = f2bf(v.z - bf2f(h.z));
  h.w = f2bf(v.w); l4.w = f2bf(v.w - bf2f(h.w));
  ((ushort4*)hi)[i] = h;
  ((ushort4*)lo)[i] = l4;
}

__global__ __launch_bounds__(256) void cast_bf16(const float* __restrict__ src,
                                                 unsigned short* __restrict__ dst) {
  long i = (long)blockIdx.x * 256 + threadIdx.x;
  float4 v = ((const float4*)src)[i];
  ushort4 h;
  h.x = f2bf(v.x); h.y = f2bf(v.y); h.z = f2bf(v.z); h.w = f2bf(v.w);
  ((ushort4*)dst)[i] = h;
}

// ---------------------------------------------------------------------------
// k-head-norm (F.normalize over HEAD axis) + split to bf16 hi/lo
// ---------------------------------------------------------------------------
__global__ __launch_bounds__(256) void knorm_split(const float* __restrict__ kf,
                                                   unsigned short* __restrict__ kn1,
                                                   unsigned short* __restrict__ kn2) {
  int t = blockIdx.x * 256 + threadIdx.x;   // 1M threads: (b, m, d)
  int b = t >> 17;
  int rem = t & 131071;
  int m = rem >> 7;
  int d = rem & 127;
  long base = (long)b * 1048576 + (long)m * 1024 + d;
  float v[8]; float s = 0.f;
  #pragma unroll
  for (int h = 0; h < 8; ++h) { v[h] = kf[base + h * 128]; s += v[h] * v[h]; }
  float rn = 1.f / fmaxf(sqrtf(s), 1e-12f);
  #pragma unroll
  for (int h = 0; h < 8; ++h) {
    float f = v[h] * rn;
    unsigned short hi = f2bf(f);
    kn1[base + h * 128] = hi;
    kn2[base + h * 128] = f2bf(f - bf2f(hi));
  }
}

// ---------------------------------------------------------------------------
// masked softmax over each 1024-row of attn (in place, f32)
// ---------------------------------------------------------------------------
__global__ __launch_bounds__(256) void softmax_mask(float* __restrict__ attn, const int* __restrict__ mask) {
  __shared__ float sred[8];
  int r = blockIdx.x;               // r = (b*8 + h)*1024 + m
  int b = r >> 13;
  int m = r & 1023;
  float* row = attn + (long)r * 1024;
  const int* mrow = mask + (long)b * 1048576 + (long)m * 1024;
  int i = threadIdx.x;
  float4 v = ((const float4*)row)[i];
  int4 mk = ((const int4*)mrow)[i];
  float x0 = mk.x ? v.x : -1e9f;
  float x1 = mk.y ? v.y : -1e9f;
  float x2 = mk.z ? v.z : -1e9f;
  float x3 = mk.w ? v.w : -1e9f;
  float mx = fmaxf(fmaxf(x0, x1), fmaxf(x2, x3));
  #pragma unroll
  for (int o = 32; o; o >>= 1) mx = fmaxf(mx, __shfl_down(mx, o, 64));
  if ((i & 63) == 0) sred[i >> 6] = mx;
  __syncthreads();
  mx = fmaxf(fmaxf(sred[0], sred[1]), fmaxf(sred[2], sred[3]));
  float e0 = __expf(x0 - mx), e1 = __expf(x1 - mx), e2 = __expf(x2 - mx), e3 = __expf(x3 - mx);
  float s = e0 + e1 + e2 + e3;
  #pragma unroll
  for (int o = 32; o; o >>= 1) s += __shfl_down(s, o, 64);
  if ((i & 63) == 0) sred[4 + (i >> 6)] = s;
  __syncthreads();
  s = sred[4] + sred[5] + sred[6] + sred[7];
  float inv = 1.f / s;
  ((float4*)row)[i] = make_float4(e0 * inv, e1 * inv, e2 * inv, e3 * inv);
}

// ---------------------------------------------------------------------------
extern "C" void kernel_launch(void* const* d_in, const int* in_sizes, int n_in,
                              void* d_out, int out_size, void* d_ws, size_t ws_size,
                              hipStream_t stream) {
  const float* enc  = (const float*)d_in[0];
  const int*   mask = (const int*)d_in[1];
  const float* ln1g = (const float*)d_in[2];
  const float* ln1b = (const float*)d_in[3];
  const float* wq   = (const float*)d_in[4];
  const float* wk   = (const float*)d_in[5];
  const float* wv   = (const float*)d_in[6];
  const float* wo   = (const float*)d_in[7];
  const float* ln2g = (const float*)d_in[8];
  const float* ln2b = (const float*)d_in[9];
  const float* w1   = (const float*)d_in[10];
  const float* b1   = (const float*)d_in[11];
  const float* w2   = (const float*)d_in[12];
  const float* b2   = (const float*)d_in[13];

  float* out_enc  = (float*)d_out;
  float* out_attn = out_enc + 8388608;   // [8, 8, 1024, 1024]

  const size_t MB = 1ull << 20;
  char* ws = (char*)d_ws;
  // workspace layout (~208 MB + 8.1 KB)
  unsigned short* h1   = (unsigned short*)(ws + 0 * MB);     // [8192,1024] bf16 hi
  unsigned short* h2   = (unsigned short*)(ws + 16 * MB);    // bf16 lo
  float*          qf   = (float*)(ws + 32 * MB);             // q f32 (later reused as x2f)
  float*          x2f  = (float*)(ws + 32 * MB);
  float*          kf   = (float*)(ws + 64 * MB);             // k f32 (later reused)
  unsigned short* h2b  = (unsigned short*)(ws + 64 * MB);    // LN2 out bf16
  unsigned short* tb   = (unsigned short*)(ws + 80 * MB);    // FFN1 out bf16
  unsigned short* q1   = (unsigned short*)(ws + 96 * MB);
  unsigned short* q2   = (unsigned short*)(ws + 112 * MB);
  unsigned short* kn1  = (unsigned short*)(ws + 128 * MB);
  unsigned short* kn2  = (unsigned short*)(ws + 144 * MB);
  unsigned short* vt   = (unsigned short*)(ws + 160 * MB);   // v^T per batch [b][o][m]
  unsigned short* outm = (unsigned short*)(ws + 176 * MB);   // attn@v merged [b][m][o]
  unsigned short* wq1  = (unsigned short*)(ws + 192 * MB);
  unsigned short* wq2  = (unsigned short*)(ws + 194 * MB);
  unsigned short* wk1  = (unsigned short*)(ws + 196 * MB);
  unsigned short* wk2  = (unsigned short*)(ws + 198 * MB);
  unsigned short* wv1  = (unsigned short*)(ws + 200 * MB);
  unsigned short* wob  = (unsigned short*)(ws + 202 * MB);
  unsigned short* w1b  = (unsigned short*)(ws + 204 * MB);
  unsigned short* w2b  = (unsigned short*)(ws + 206 * MB);
  float2* part  = (float2*)(ws + 208 * MB);                  // 1024 float2
  float2* stats = part + 1024;                               // 8 float2

  const float invN = 1.f / 1048576.f;

  // ---- LN1 + split ----
  ln_stats1<<<dim3(128, 8), 256, 0, stream>>>(enc, part);
  ln_stats2<<<dim3(8), 128, 0, stream>>>(part, stats, invN, 1e-6f);
  ln_apply<true><<<dim3(8192), 256, 0, stream>>>(enc, ln1g, ln1b, stats, h1, h2);

  // ---- weight casts ----
  split_bf16<<<dim3(1024), 256, 0, stream>>>(wq, wq1, wq2);
  split_bf16<<<dim3(1024), 256, 0, stream>>>(wk, wk1, wk2);
  cast_bf16 <<<dim3(1024), 256, 0, stream>>>(wv, wv1);
  cast_bf16 <<<dim3(1024), 256, 0, stream>>>(wo, wob);
  cast_bf16 <<<dim3(1024), 256, 0, stream>>>(w1, w1b);
  cast_bf16 <<<dim3(1024), 256, 0, stream>>>(w2, w2b);

  // ---- q/k projections (split-bf16, 3 passes each -> f32) ----
  gemm_bt<0, false, false><<<dim3(512, 1, 1), 256, 0, stream>>>(h1, wq1, qf, nullptr, nullptr,
      8192, 1024, 1024, 1024, 1024, 1024, 1, 0, 0, 0, 0, 0, 0);
  gemm_bt<0, true,  false><<<dim3(512, 1, 1), 256, 0, stream>>>(h1, wq2, qf, nullptr, nullptr,
      8192, 1024, 1024, 1024, 1024, 1024, 1, 0, 0, 0, 0, 0, 0);
  gemm_bt<0, true,  false><<<dim3(512, 1, 1), 256, 0, stream>>>(h2, wq1, qf, nullptr, nullptr,
      8192, 1024, 1024, 1024, 1024, 1024, 1, 0, 0, 0, 0, 0, 0);
  gemm_bt<0, false, false><<<dim3(512, 1, 1), 256, 0, stream>>>(h1, wk1, kf, nullptr, nullptr,
      8192, 1024, 1024, 1024, 1024, 1024, 1, 0, 0, 0, 0, 0, 0);
  gemm_bt<0, true,  false><<<dim3(512, 1, 1), 256, 0, stream>>>(h1, wk2, kf, nullptr, nullptr,
      8192, 1024, 1024, 1024, 1024, 1024, 1, 0, 0, 0, 0, 0, 0);
  gemm_bt<0, true,  false><<<dim3(512, 1, 1), 256, 0, stream>>>(h2, wk1, kf, nullptr, nullptr,
      8192, 1024, 1024, 1024, 1024, 1024, 1, 0, 0, 0, 0, 0, 0);

  // ---- v projection -> v^T bf16 (per batch) ----
  gemm_bt<2, false, false><<<dim3(64, 1, 8), 256, 0, stream>>>(h1, wv1, vt, nullptr, nullptr,
      1024, 1024, 1024, 1024, 1024, 1024, 1, 1048576, 0, 0, 0, 1048576, 0);

  // ---- splits for the score path ----
  split_bf16<<<dim3(8192), 256, 0, stream>>>(qf, q1, q2);
  knorm_split<<<dim3(4096), 256, 0, stream>>>(kf, kn1, kn2);

  // ---- logits q . kn^T (split, 3 passes), batched over (b,h) ----
  gemm_bt<0, false, false><<<dim3(64, 1, 64), 256, 0, stream>>>(q1, kn1, out_attn, nullptr, nullptr,
      1024, 1024, 128, 1024, 1024, 1024, 8, 1048576, 128, 1048576, 128, 8388608, 1048576);
  gemm_bt<0, true,  false><<<dim3(64, 1, 64), 256, 0, stream>>>(q1, kn2, out_attn, nullptr, nullptr,
      1024, 1024, 128, 1024, 1024, 1024, 8, 1048576, 128, 1048576, 128, 8388608, 1048576);
  gemm_bt<0, true,  false><<<dim3(64, 1, 64), 256, 0, stream>>>(q2, kn1, out_attn, nullptr, nullptr,
      1024, 1024, 128, 1024, 1024, 1024, 8, 1048576, 128, 1048576, 128, 8388608, 1048576);

  // ---- mask + softmax (in place on d_out attn region) ----
  softmax_mask<<<dim3(65536), 256, 0, stream>>>(out_attn, mask);

  // ---- PV: attn(f32) @ v -> merged [b][m][h*128+d] bf16 ----
  gemm_bt<1, false, true><<<dim3(8, 1, 64), 256, 0, stream>>>(out_attn, vt, outm, nullptr, nullptr,
      1024, 128, 1024, 1024, 1024, 1024, 8, 8388608, 1048576, 1048576, 131072, 1048576, 128);

  // ---- output projection + residual ----
  gemm_bt<3, false, false><<<dim3(512, 1, 1), 256, 0, stream>>>(outm, wob, x2f, nullptr, enc,
      8192, 1024, 1024, 1024, 1024, 1024, 1, 0, 0, 0, 0, 0, 0);

  // ---- LN2 ----
  ln_stats1<<<dim3(128, 8), 256, 0, stream>>>(x2f, part);
  ln_stats2<<<dim3(8), 128, 0, stream>>>(part, stats, invN, 1e-6f);
  ln_apply<false><<<dim3(8192), 256, 0, stream>>>(x2f, ln2g, ln2b, stats, h2b, nullptr);

  // ---- FFN ----
  gemm_bt<4, false, false><<<dim3(512, 1, 1), 256, 0, stream>>>(h2b, w1b, tb, b1, nullptr,
      8192, 1024, 1024, 1024, 1024, 1024, 1, 0, 0, 0, 0, 0, 0);
  gemm_bt<5, false, false><<<dim3(512, 1, 1), 256, 0, stream>>>(tb, w2b, out_enc, b2, x2f,
      8192, 1024, 1024, 1024, 1024, 1024, 1, 0, 0, 0, 0, 0, 0);
}

// Round 2
// 619.584 us; speedup vs baseline: 1.9730x; 1.9730x over previous
//
#include <hip/hip_runtime.h>

#define DEVINL __device__ __forceinline__

typedef __bf16 bf16x8 __attribute__((ext_vector_type(8)));
typedef float  f32x4  __attribute__((ext_vector_type(4)));

DEVINL unsigned short f2bf(float f) {
  union { float f; unsigned int u; } v; v.f = f;
  unsigned int u = v.u;
  return (unsigned short)((u + 0x7fffu + ((u >> 16) & 1u)) >> 16);
}
DEVINL float bf2f(unsigned short b) {
  union { unsigned int u; float f; } v; v.u = ((unsigned int)b) << 16;
  return v.f;
}
DEVINL __bf16 fbf(float f) {
  unsigned short u = f2bf(f);
  return __builtin_bit_cast(__bf16, u);
}

#define GLD_LDS16(SRC, DST) \
  __builtin_amdgcn_global_load_lds((const __attribute__((address_space(1))) void*)(SRC), \
                                   (__attribute__((address_space(3))) void*)(DST), 16, 0, 0)

// ---------------------------------------------------------------------------
// Plain bf16 GEMM: C[M,N] = A[M,K] * B[N,K]^T
// EPI: 1=bf16 store, 2=bf16 transposed store (LDS-transposed, coalesced),
//      3=f32 store + res, 4=bf16 relu(x+bias), 5=f32 x+bias+res
// AF32: A operand is f32 in memory (converted to bf16 after LDS staging).
// ---------------------------------------------------------------------------
template<int EPI, bool AF32>
__global__ __launch_bounds__(256) void gemm_bt(
    const void* __restrict__ Ap, const unsigned short* __restrict__ Bp, void* __restrict__ Cp,
    const float* __restrict__ bias, const float* __restrict__ res,
    int M, int N, int K, int lda, int ldb, int ldc, int H,
    long sAb, long sAh, long sBb, long sBh, long sCb, long sCh)
{
  constexpr int ABYTES = AF32 ? 16384 : 8192;
  constexpr int SMEMSZ = (EPI == 2) ? 34816 : (ABYTES + 8192);
  __shared__ __align__(16) char smem[SMEMSZ];
  unsigned short* sB = (unsigned short*)(smem + ABYTES);

  const int tid = threadIdx.x;
  const int w = tid >> 6, l = tid & 63;
  const int wr = w >> 1, wc = w & 1;
  const int ntn = N >> 7;
  const int tm = (int)blockIdx.x / ntn;
  const int tn = (int)blockIdx.x - tm * ntn;
  const int z = blockIdx.z;
  const int bb = z / H, hh = z - bb * H;
  const long offA = (long)bb * sAb + (long)hh * sAh;
  const long offB = (long)bb * sBb + (long)hh * sBh;
  const long offC = (long)bb * sCb + (long)hh * sCh;

  f32x4 zero = {0.f, 0.f, 0.f, 0.f};
  f32x4 acc[4][4];
  #pragma unroll
  for (int m = 0; m < 4; ++m)
    #pragma unroll
    for (int n = 0; n < 4; ++n) acc[m][n] = zero;

  for (int k0 = 0; k0 < K; k0 += 32) {
    __syncthreads();
    if constexpr (!AF32) {
      const unsigned short* A = (const unsigned short*)Ap;
      const int rl = l >> 2, cl = (l & 3) << 3;
      #pragma unroll
      for (int i = 0; i < 2; ++i) {
        const unsigned short* src = A + offA + (long)(tm*128 + w*32 + i*16 + rl) * lda + (k0 + cl);
        unsigned short* dst = (unsigned short*)smem + (w*32 + i*16) * 32;
        GLD_LDS16(src, dst);
      }
    } else {
      const float* A = (const float*)Ap;
      const int rl = l >> 3, cl = (l & 7) << 2;
      #pragma unroll
      for (int i = 0; i < 4; ++i) {
        const float* src = A + offA + (long)(tm*128 + w*32 + i*8 + rl) * lda + (k0 + cl);
        float* dst = (float*)smem + (w*32 + i*8) * 32;
        GLD_LDS16(src, dst);
      }
    }
    {
      const int rl = l >> 2, cl = (l & 3) << 3;
      #pragma unroll
      for (int i = 0; i < 2; ++i) {
        const unsigned short* src = Bp + offB + (long)(tn*128 + w*32 + i*16 + rl) * ldb + (k0 + cl);
        unsigned short* dst = sB + (w*32 + i*16) * 32;
        GLD_LDS16(src, dst);
      }
    }
    __syncthreads();

    bf16x8 af[4], bfr[4];
    if constexpr (!AF32) {
      const unsigned short* sA = (const unsigned short*)smem;
      #pragma unroll
      for (int m = 0; m < 4; ++m) {
        int row = wr*64 + m*16 + (l & 15);
        af[m] = *(const bf16x8*)(sA + row*32 + ((l >> 4) << 3));
      }
    } else {
      const float* sA = (const float*)smem;
      #pragma unroll
      for (int m = 0; m < 4; ++m) {
        int row = wr*64 + m*16 + (l & 15);
        const float* p = sA + row*32 + ((l >> 4) << 3);
        f32x4 v0 = *(const f32x4*)p;
        f32x4 v1 = *(const f32x4*)(p + 4);
        bf16x8 t;
        t[0]=fbf(v0[0]); t[1]=fbf(v0[1]); t[2]=fbf(v0[2]); t[3]=fbf(v0[3]);
        t[4]=fbf(v1[0]); t[5]=fbf(v1[1]); t[6]=fbf(v1[2]); t[7]=fbf(v1[3]);
        af[m] = t;
      }
    }
    #pragma unroll
    for (int n = 0; n < 4; ++n) {
      int row = wc*64 + n*16 + (l & 15);
      bfr[n] = *(const bf16x8*)(sB + row*32 + ((l >> 4) << 3));
    }
    #pragma unroll
    for (int m = 0; m < 4; ++m)
      #pragma unroll
      for (int n = 0; n < 4; ++n)
        acc[m][n] = __builtin_amdgcn_mfma_f32_16x16x32_bf16(af[m], bfr[n], acc[m][n], 0, 0, 0);
  }

  if constexpr (EPI == 2) {
    // LDS transpose -> coalesced 16B stores of C^T
    __syncthreads();
    unsigned short* sT = (unsigned short*)smem;
    #pragma unroll
    for (int m = 0; m < 4; ++m)
      #pragma unroll
      for (int n = 0; n < 4; ++n)
        #pragma unroll
        for (int r = 0; r < 4; ++r) {
          int rowl = wr*64 + m*16 + ((l >> 4) << 2) + r;
          int coll = wc*64 + n*16 + (l & 15);
          sT[coll*136 + rowl] = f2bf(acc[m][n][r]);
        }
    __syncthreads();
    #pragma unroll
    for (int i = 0; i < 8; ++i) {
      int idx = tid + i*256;
      int c = idx >> 4, ch = idx & 15;
      bf16x8 vv = *(const bf16x8*)(sT + c*136 + ch*8);
      *(bf16x8*)((unsigned short*)Cp + offC + (long)(tn*128 + c)*ldc + (tm*128 + ch*8)) = vv;
    }
  } else {
    #pragma unroll
    for (int m = 0; m < 4; ++m) {
      #pragma unroll
      for (int n = 0; n < 4; ++n) {
        #pragma unroll
        for (int r = 0; r < 4; ++r) {
          int row = tm*128 + wr*64 + m*16 + ((l >> 4) << 2) + r;
          int col = tn*128 + wc*64 + n*16 + (l & 15);
          float v = acc[m][n][r];
          long ci = offC + (long)row * ldc + col;
          if constexpr (EPI == 1) {
            ((unsigned short*)Cp)[ci] = f2bf(v);
          } else if constexpr (EPI == 3) {
            ((float*)Cp)[ci] = v + res[ci];
          } else if constexpr (EPI == 4) {
            ((unsigned short*)Cp)[ci] = f2bf(fmaxf(v + bias[col], 0.f));
          } else if constexpr (EPI == 5) {
            ((float*)Cp)[ci] = v + bias[col] + res[ci];
          }
        }
      }
    }
  }
}

// ---------------------------------------------------------------------------
// Fused split-precision GEMM: C = (A1+A2) * (B1+B2)^T, dropping A2*B2.
// One pass, 3 MFMA products per fragment pair.
// EPI: 0 = f32 store, 6 = split bf16 store (hi->Cp, lo->Cp2)
// ---------------------------------------------------------------------------
template<int EPI>
__global__ __launch_bounds__(256) void gemm_split(
    const unsigned short* __restrict__ A1, const unsigned short* __restrict__ A2,
    const unsigned short* __restrict__ B1, const unsigned short* __restrict__ B2,
    void* __restrict__ Cp, unsigned short* __restrict__ Cp2,
    int M, int N, int K, int lda, int ldb, int ldc, int H,
    long sAb, long sAh, long sBb, long sBh, long sCb, long sCh)
{
  __shared__ __align__(16) unsigned short sAll[4 * 4096];
  unsigned short* sA1 = sAll;
  unsigned short* sA2 = sAll + 4096;
  unsigned short* sB1 = sAll + 8192;
  unsigned short* sB2 = sAll + 12288;

  const int tid = threadIdx.x;
  const int w = tid >> 6, l = tid & 63;
  const int wr = w >> 1, wc = w & 1;
  const int ntn = N >> 7;
  const int tm = (int)blockIdx.x / ntn;
  const int tn = (int)blockIdx.x - tm * ntn;
  const int z = blockIdx.z;
  const int bb = z / H, hh = z - bb * H;
  const long offA = (long)bb * sAb + (long)hh * sAh;
  const long offB = (long)bb * sBb + (long)hh * sBh;
  const long offC = (long)bb * sCb + (long)hh * sCh;

  f32x4 zero = {0.f, 0.f, 0.f, 0.f};
  f32x4 acc[4][4];
  #pragma unroll
  for (int m = 0; m < 4; ++m)
    #pragma unroll
    for (int n = 0; n < 4; ++n) acc[m][n] = zero;

  const int rl = l >> 2, cl = (l & 3) << 3;

  for (int k0 = 0; k0 < K; k0 += 32) {
    __syncthreads();
    #pragma unroll
    for (int i = 0; i < 2; ++i) {
      const int row = w*32 + i*16;                 // wave-uniform
      const long asrc = offA + (long)(tm*128 + row + rl) * lda + (k0 + cl);
      const long bsrc = offB + (long)(tn*128 + row + rl) * ldb + (k0 + cl);
      GLD_LDS16(A1 + asrc, sA1 + row*32);
      GLD_LDS16(A2 + asrc, sA2 + row*32);
      GLD_LDS16(B1 + bsrc, sB1 + row*32);
      GLD_LDS16(B2 + bsrc, sB2 + row*32);
    }
    __syncthreads();

    bf16x8 a1[4], a2[4], bb4[4];
    int aoff[4], boff[4];
    #pragma unroll
    for (int m = 0; m < 4; ++m) {
      int row = wr*64 + m*16 + (l & 15);
      aoff[m] = row*32 + ((l >> 4) << 3);
      a1[m] = *(const bf16x8*)(sA1 + aoff[m]);
      a2[m] = *(const bf16x8*)(sA2 + aoff[m]);
    }
    #pragma unroll
    for (int n = 0; n < 4; ++n) {
      int row = wc*64 + n*16 + (l & 15);
      boff[n] = row*32 + ((l >> 4) << 3);
      bb4[n] = *(const bf16x8*)(sB1 + boff[n]);
    }
    #pragma unroll
    for (int m = 0; m < 4; ++m)
      #pragma unroll
      for (int n = 0; n < 4; ++n) {
        acc[m][n] = __builtin_amdgcn_mfma_f32_16x16x32_bf16(a1[m], bb4[n], acc[m][n], 0, 0, 0);
        acc[m][n] = __builtin_amdgcn_mfma_f32_16x16x32_bf16(a2[m], bb4[n], acc[m][n], 0, 0, 0);
      }
    #pragma unroll
    for (int n = 0; n < 4; ++n)
      bb4[n] = *(const bf16x8*)(sB2 + boff[n]);
    #pragma unroll
    for (int m = 0; m < 4; ++m)
      #pragma unroll
      for (int n = 0; n < 4; ++n)
        acc[m][n] = __builtin_amdgcn_mfma_f32_16x16x32_bf16(a1[m], bb4[n], acc[m][n], 0, 0, 0);
  }

  #pragma unroll
  for (int m = 0; m < 4; ++m) {
    #pragma unroll
    for (int n = 0; n < 4; ++n) {
      #pragma unroll
      for (int r = 0; r < 4; ++r) {
        int row = tm*128 + wr*64 + m*16 + ((l >> 4) << 2) + r;
        int col = tn*128 + wc*64 + n*16 + (l & 15);
        float v = acc[m][n][r];
        long ci = offC + (long)row * ldc + col;
        if constexpr (EPI == 0) {
          ((float*)Cp)[ci] = v;
        } else {   // EPI 6: split bf16
          unsigned short hv = f2bf(v);
          ((unsigned short*)Cp)[ci] = hv;
          Cp2[ci] = f2bf(v - bf2f(hv));
        }
      }
    }
  }
}

// ---------------------------------------------------------------------------
// LayerNorm over (d_model, seq) per batch: two-stage deterministic reduction.
// ---------------------------------------------------------------------------
__global__ __launch_bounds__(256) void ln_stats1(const float* __restrict__ x, float2* __restrict__ part) {
  __shared__ float2 sred[4];
  int b = blockIdx.y, blk = blockIdx.x;
  const float4* xp = (const float4*)(x + (long)b * 1048576 + (long)blk * 8192);
  float s = 0.f, ss = 0.f;
  for (int i = threadIdx.x; i < 2048; i += 256) {
    float4 v = xp[i];
    s  += v.x + v.y + v.z + v.w;
    ss += v.x*v.x + v.y*v.y + v.z*v.z + v.w*v.w;
  }
  #pragma unroll
  for (int o = 32; o; o >>= 1) { s += __shfl_down(s, o, 64); ss += __shfl_down(ss, o, 64); }
  if ((threadIdx.x & 63) == 0) sred[threadIdx.x >> 6] = make_float2(s, ss);
  __syncthreads();
  if (threadIdx.x == 0) {
    float S = 0.f, SS = 0.f;
    #pragma unroll
    for (int j = 0; j < 4; ++j) { S += sred[j].x; SS += sred[j].y; }
    part[b * 128 + blk] = make_float2(S, SS);
  }
}

__global__ __launch_bounds__(128) void ln_stats2(const float2* __restrict__ part, float2* __restrict__ stats,
                                                 float invN, float eps) {
  __shared__ float2 tmp[2];
  int b = blockIdx.x;
  float2 p = part[b * 128 + threadIdx.x];
  float s = p.x, ss = p.y;
  #pragma unroll
  for (int o = 32; o; o >>= 1) { s += __shfl_down(s, o, 64); ss += __shfl_down(ss, o, 64); }
  if ((threadIdx.x & 63) == 0) tmp[threadIdx.x >> 6] = make_float2(s, ss);
  __syncthreads();
  if (threadIdx.x == 0) {
    float S = tmp[0].x + tmp[1].x, SS = tmp[0].y + tmp[1].y;
    float mu = S * invN;
    float var = SS * invN - mu * mu;
    stats[b] = make_float2(mu, rsqrtf(var + eps));
  }
}

template<bool LO>
__global__ __launch_bounds__(256) void ln_apply(const float* __restrict__ x, const float* __restrict__ g,
                                                const float* __restrict__ be, const float2* __restrict__ stats,
                                                unsigned short* __restrict__ hi, unsigned short* __restrict__ lo) {
  long i = (long)blockIdx.x * 256 + threadIdx.x;
  long e = i << 2;
  int b   = (int)(e >> 20);
  int rem = (int)(e & 1048575);
  float2 st = stats[b];
  float4 xv = ((const float4*)x)[i];
  float4 gv = *(const float4*)(g + rem);
  float4 bv = *(const float4*)(be + rem);
  float h0 = (xv.x - st.x) * st.y * gv.x + bv.x;
  float h1 = (xv.y - st.x) * st.y * gv.y + bv.y;
  float h2 = (xv.z - st.x) * st.y * gv.z + bv.z;
  float h3 = (xv.w - st.x) * st.y * gv.w + bv.w;
  ushort4 h;
  h.x = f2bf(h0); h.y = f2bf(h1); h.z = f2bf(h2); h.w = f2bf(h3);
  ((ushort4*)hi)[i] = h;
  if (LO) {
    ushort4 l4;
    l4.x = f2bf(h0 - bf2f(h.x)); l4.y = f2bf(h1 - bf2f(h.y));
    l4.z = f2bf(h2 - bf2f(h.z)); l4.w = f2bf(h3 - bf2f(h.w));
    ((ushort4*)lo)[i] = l4;
  }
}

__global__ __launch_bounds__(256) void split_bf16(const float* __restrict__ src,
                                                  unsigned short* __restrict__ hi,
                                                  unsigned short* __restrict__ lo) {
  long i = (long)blockIdx.x * 256 + threadIdx.x;
  float4 v = ((const float4*)src)[i];
  ushort4 h, l4;
  h.x = f2bf(v.x); l4.x = f2bf(v.x - bf2f(h.x));
  h.y = f2bf(v.y); l4.y = f2bf(v.y - bf2f(h.y));
  h.z = f2bf(v.z); l4.z = f2bf(v.z - bf2f(h.z));
  h.w = f2bf(v.w); l4.w = f2bf(v.w - bf2f(h.w));
  ((ushort4*)hi)[i] = h;
  ((ushort4*)lo)[i] = l4;
}

__global__ __launch_bounds__(256) void cast_bf16(const float* __restrict__ src,
                                                 unsigned short* __restrict__ dst) {
  long i = (long)blockIdx.x * 256 + threadIdx.x;
  float4 v = ((const float4*)src)[i];
  ushort4 h;
  h.x = f2bf(v.x); h.y = f2bf(v.y); h.z = f2bf(v.z); h.w = f2bf(v.w);
  ((ushort4*)dst)[i] = h;
}

// k-head-norm from split bf16 k (hi+lo reconstruct), write split kn
__global__ __launch_bounds__(256) void knorm_split2(const unsigned short* __restrict__ k1,
                                                    const unsigned short* __restrict__ k2,
                                                    unsigned short* __restrict__ kn1,
                                                    unsigned short* __restrict__ kn2) {
  int t = blockIdx.x * 256 + threadIdx.x;   // 1M threads: (b, m, d)
  int b = t >> 17;
  int rem = t & 131071;
  int m = rem >> 7;
  int d = rem & 127;
  long base = (long)b * 1048576 + (long)m * 1024 + d;
  float v[8]; float s = 0.f;
  #pragma unroll
  for (int h = 0; h < 8; ++h) {
    v[h] = bf2f(k1[base + h * 128]) + bf2f(k2[base + h * 128]);
    s += v[h] * v[h];
  }
  float rn = 1.f / fmaxf(sqrtf(s), 1e-12f);
  #pragma unroll
  for (int h = 0; h < 8; ++h) {
    float f = v[h] * rn;
    unsigned short hv = f2bf(f);
    kn1[base + h * 128] = hv;
    kn2[base + h * 128] = f2bf(f - bf2f(hv));
  }
}

// masked softmax over each 1024-row of attn (in place, f32)
__global__ __launch_bounds__(256) void softmax_mask(float* __restrict__ attn, const int* __restrict__ mask) {
  __shared__ float sred[8];
  int r = blockIdx.x;
  int b = r >> 13;
  int m = r & 1023;
  float* row = attn + (long)r * 1024;
  const int* mrow = mask + (long)b * 1048576 + (long)m * 1024;
  int i = threadIdx.x;
  float4 v = ((const float4*)row)[i];
  int4 mk = ((const int4*)mrow)[i];
  float x0 = mk.x ? v.x : -1e9f;
  float x1 = mk.y ? v.y : -1e9f;
  float x2 = mk.z ? v.z : -1e9f;
  float x3 = mk.w ? v.w : -1e9f;
  float mx = fmaxf(fmaxf(x0, x1), fmaxf(x2, x3));
  #pragma unroll
  for (int o = 32; o; o >>= 1) mx = fmaxf(mx, __shfl_down(mx, o, 64));
  if ((i & 63) == 0) sred[i >> 6] = mx;
  __syncthreads();
  mx = fmaxf(fmaxf(sred[0], sred[1]), fmaxf(sred[2], sred[3]));
  float e0 = __expf(x0 - mx), e1 = __expf(x1 - mx), e2 = __expf(x2 - mx), e3 = __expf(x3 - mx);
  float s = e0 + e1 + e2 + e3;
  #pragma unroll
  for (int o = 32; o; o >>= 1) s += __shfl_down(s, o, 64);
  if ((i & 63) == 0) sred[4 + (i >> 6)] = s;
  __syncthreads();
  s = sred[4] + sred[5] + sred[6] + sred[7];
  float inv = 1.f / s;
  ((float4*)row)[i] = make_float4(e0 * inv, e1 * inv, e2 * inv, e3 * inv);
}

// ---------------------------------------------------------------------------
extern "C" void kernel_launch(void* const* d_in, const int* in_sizes, int n_in,
                              void* d_out, int out_size, void* d_ws, size_t ws_size,
                              hipStream_t stream) {
  const float* enc  = (const float*)d_in[0];
  const int*   mask = (const int*)d_in[1];
  const float* ln1g = (const float*)d_in[2];
  const float* ln1b = (const float*)d_in[3];
  const float* wq   = (const float*)d_in[4];
  const float* wk   = (const float*)d_in[5];
  const float* wv   = (const float*)d_in[6];
  const float* wo   = (const float*)d_in[7];
  const float* ln2g = (const float*)d_in[8];
  const float* ln2b = (const float*)d_in[9];
  const float* w1   = (const float*)d_in[10];
  const float* b1   = (const float*)d_in[11];
  const float* w2   = (const float*)d_in[12];
  const float* b2   = (const float*)d_in[13];

  float* out_enc  = (float*)d_out;
  float* out_attn = out_enc + 8388608;   // [8, 8, 1024, 1024]

  const size_t MB = 1ull << 20;
  char* ws = (char*)d_ws;
  unsigned short* h1   = (unsigned short*)(ws + 0 * MB);     // LN1 hi  [8192,1024]
  unsigned short* h2   = (unsigned short*)(ws + 16 * MB);    // LN1 lo
  unsigned short* q1   = (unsigned short*)(ws + 32 * MB);    // q hi (later h2b)
  unsigned short* q2   = (unsigned short*)(ws + 48 * MB);    // q lo (later tb)
  unsigned short* k1r  = (unsigned short*)(ws + 64 * MB);    // k hi (raw)
  unsigned short* k2r  = (unsigned short*)(ws + 80 * MB);    // k lo (raw)
  unsigned short* kn1  = (unsigned short*)(ws + 96 * MB);    // k-normed hi
  unsigned short* kn2  = (unsigned short*)(ws + 112 * MB);   // k-normed lo
  unsigned short* vt   = (unsigned short*)(ws + 128 * MB);   // v^T per batch [b][o][m]
  unsigned short* outm = (unsigned short*)(ws + 144 * MB);   // attn@v merged [b][m][o]
  float*          x2f  = (float*)(ws + 160 * MB);            // attn-out + residual, f32
  unsigned short* h2b  = (unsigned short*)(ws + 32 * MB);    // LN2 out bf16 (reuse q1)
  unsigned short* tb   = (unsigned short*)(ws + 48 * MB);    // FFN1 out bf16 (reuse q2)
  unsigned short* wq1  = (unsigned short*)(ws + 192 * MB);
  unsigned short* wq2  = (unsigned short*)(ws + 194 * MB);
  unsigned short* wk1  = (unsigned short*)(ws + 196 * MB);
  unsigned short* wk2  = (unsigned short*)(ws + 198 * MB);
  unsigned short* wv1  = (unsigned short*)(ws + 200 * MB);
  unsigned short* wob  = (unsigned short*)(ws + 202 * MB);
  unsigned short* w1b  = (unsigned short*)(ws + 204 * MB);
  unsigned short* w2b  = (unsigned short*)(ws + 206 * MB);
  float2* part  = (float2*)(ws + 208 * MB);
  float2* stats = part + 1024;

  const float invN = 1.f / 1048576.f;

  // ---- LN1 + split ----
  ln_stats1<<<dim3(128, 8), 256, 0, stream>>>(enc, part);
  ln_stats2<<<dim3(8), 128, 0, stream>>>(part, stats, invN, 1e-6f);
  ln_apply<true><<<dim3(8192), 256, 0, stream>>>(enc, ln1g, ln1b, stats, h1, h2);

  // ---- weight casts ----
  split_bf16<<<dim3(1024), 256, 0, stream>>>(wq, wq1, wq2);
  split_bf16<<<dim3(1024), 256, 0, stream>>>(wk, wk1, wk2);
  cast_bf16 <<<dim3(1024), 256, 0, stream>>>(wv, wv1);
  cast_bf16 <<<dim3(1024), 256, 0, stream>>>(wo, wob);
  cast_bf16 <<<dim3(1024), 256, 0, stream>>>(w1, w1b);
  cast_bf16 <<<dim3(1024), 256, 0, stream>>>(w2, w2b);

  // ---- q/k projections: ONE fused split pass each, split-bf16 output ----
  gemm_split<6><<<dim3(512, 1, 1), 256, 0, stream>>>(h1, h2, wq1, wq2, q1, q2,
      8192, 1024, 1024, 1024, 1024, 1024, 1, 0, 0, 0, 0, 0, 0);
  gemm_split<6><<<dim3(512, 1, 1), 256, 0, stream>>>(h1, h2, wk1, wk2, k1r, k2r,
      8192, 1024, 1024, 1024, 1024, 1024, 1, 0, 0, 0, 0, 0, 0);

  // ---- v projection -> v^T bf16 (per batch), LDS-transposed stores ----
  gemm_bt<2, false><<<dim3(64, 1, 8), 256, 0, stream>>>(h1, wv1, vt, nullptr, nullptr,
      1024, 1024, 1024, 1024, 1024, 1024, 1, 1048576, 0, 0, 0, 1048576, 0);

  // ---- k head-norm + split ----
  knorm_split2<<<dim3(4096), 256, 0, stream>>>(k1r, k2r, kn1, kn2);

  // ---- logits q . kn^T : ONE fused split pass, f32 to d_out ----
  gemm_split<0><<<dim3(64, 1, 64), 256, 0, stream>>>(q1, q2, kn1, kn2, out_attn, nullptr,
      1024, 1024, 128, 1024, 1024, 1024, 8, 1048576, 128, 1048576, 128, 8388608, 1048576);

  // ---- mask + softmax (in place on d_out attn region) ----
  softmax_mask<<<dim3(65536), 256, 0, stream>>>(out_attn, mask);

  // ---- PV: attn(f32) @ v -> merged [b][m][h*128+d] bf16 ----
  gemm_bt<1, true><<<dim3(8, 1, 64), 256, 0, stream>>>(out_attn, vt, outm, nullptr, nullptr,
      1024, 128, 1024, 1024, 1024, 1024, 8, 8388608, 1048576, 1048576, 131072, 1048576, 128);

  // ---- output projection + residual ----
  gemm_bt<3, false><<<dim3(512, 1, 1), 256, 0, stream>>>(outm, wob, x2f, nullptr, enc,
      8192, 1024, 1024, 1024, 1024, 1024, 1, 0, 0, 0, 0, 0, 0);

  // ---- LN2 ----
  ln_stats1<<<dim3(128, 8), 256, 0, stream>>>(x2f, part);
  ln_stats2<<<dim3(8), 128, 0, stream>>>(part, stats, invN, 1e-6f);
  ln_apply<false><<<dim3(8192), 256, 0, stream>>>(x2f, ln2g, ln2b, stats, h2b, nullptr);

  // ---- FFN ----
  gemm_bt<4, false><<<dim3(512, 1, 1), 256, 0, stream>>>(h2b, w1b, tb, b1, nullptr,
      8192, 1024, 1024, 1024, 1024, 1024, 1, 0, 0, 0, 0, 0, 0);
  gemm_bt<5, false><<<dim3(512, 1, 1), 256, 0, stream>>>(tb, w2b, out_enc, b2, x2f,
      8192, 1024, 1024, 1024, 1024, 1024, 1, 0, 0, 0, 0, 0, 0);
}